// Round 7
// baseline (247.261 us; speedup 1.0000x reference)
//
#include <hip/hip_runtime.h>
#include <hip/hip_fp16.h>

#define D 128
#define NEG_SLOPE 0.2f
#define WT_STRIDE 136   // fp16 elems; dword stride 68 -> fragment reads only 2-way (free)

typedef __attribute__((ext_vector_type(8))) _Float16 v8h;
typedef __attribute__((ext_vector_type(4))) float v4f;

// ---------------- CSR build (rank-based, atomic only in fused hist) ----------------

__global__ __launch_bounds__(256) void partial_kernel(const int* __restrict__ deg,
                                                      int* __restrict__ psum, int N) {
  __shared__ int s[256];
  int t = threadIdx.x;
  int i = blockIdx.x * 256 + t;
  s[t] = (i < N) ? deg[i] : 0;
  __syncthreads();
  #pragma unroll
  for (int o = 128; o; o >>= 1) { if (t < o) s[t] += s[t + o]; __syncthreads(); }
  if (t == 0) psum[blockIdx.x] = s[0];
}

__global__ __launch_bounds__(1024) void scan_partials(const int* __restrict__ psum,
                                                      int* __restrict__ bbase,
                                                      int* __restrict__ off, int NB, int N) {
  __shared__ int s[1024];
  int t = threadIdx.x;
  int v = (t < NB) ? psum[t] : 0;
  s[t] = v;
  __syncthreads();
  for (int o = 1; o < 1024; o <<= 1) {
    int u = (t >= o) ? s[t - o] : 0;
    __syncthreads();
    s[t] += u;
    __syncthreads();
  }
  if (t < NB) bbase[t] = s[t] - v;
  if (t == 1023) off[N] = s[1023];
}

__global__ __launch_bounds__(256) void offs_kernel(const int* __restrict__ deg,
                                                   const int* __restrict__ bbase,
                                                   int* __restrict__ off, int N) {
  __shared__ int s[256];
  int t = threadIdx.x;
  int i = blockIdx.x * 256 + t;
  int v = (i < N) ? deg[i] : 0;
  s[t] = v;
  __syncthreads();
  #pragma unroll
  for (int o = 1; o < 256; o <<= 1) {
    int u = (t >= o) ? s[t - o] : 0;
    __syncthreads();
    s[t] += u;
    __syncthreads();
  }
  if (i < N) off[i] = bbase[blockIdx.x] + s[t] - v;
}

// atomic-free scatter (rank precomputed in fused hist)
__global__ __launch_bounds__(256) void scatter_kernel(
    const int* __restrict__ src, const int* __restrict__ dst,
    const int* __restrict__ rank, int E, int N,
    const int* __restrict__ off, int* __restrict__ csr) {
  int i = blockIdx.x * blockDim.x + threadIdx.x;
  if (i >= E + N) return;
  int s, d;
  if (i < E) { s = src[i]; d = dst[i]; } else { s = i - E; d = s; }
  csr[off[d] + rank[i]] = s;
}

// ---------------- MFMA GEMM(+scores) || histogram+rank ----------------
// Blocks [0,nbGemm): H^T-tile GEMM via mfma_f32_16x16x32_f16 with swapped
// operands: A_op = W^T (from LDS, fp16), B_op = X rows (global, fp16 or
// fp32->fp16). D[m][n]: n(=lane&15) is the X row -> contiguous H stores and
// shuffle-free score epilogue. Tile 9 = [wa_src; wa_dst] where wa = W@a
// (precomputed per block, L2-hot); rows 2..15 of that tile are unread garbage.
// Blocks [nbGemm,..): grid-stride histogram rank[i]=atomicAdd(&deg[dst],1).

__global__ __launch_bounds__(256, 2) void gemm_hist_fused(
    const float* __restrict__ Xf, const __half* __restrict__ Xh,
    const float* __restrict__ W,
    const float* __restrict__ avs, const float* __restrict__ avd,
    __half* __restrict__ H, float* __restrict__ Ss, float* __restrict__ Sd, int N,
    const int* __restrict__ dstE, int E, int* __restrict__ deg, int* __restrict__ rank,
    int nbGemm, int nbHist)
{
  if (blockIdx.x >= nbGemm) {
    if (dstE == nullptr) return;               // gemm-only launch
    int b = blockIdx.x - nbGemm;
    int EP = E + N;
    int stride = nbHist * 256;
    for (int i = b * 256 + (int)threadIdx.x; i < EP; i += stride) {
      int d = (i < E) ? dstE[i] : (i - E);
      rank[i] = atomicAdd(&deg[d], 1);
    }
    return;
  }

  __shared__ _Float16 Wt[128][WT_STRIDE];  // Wt[n][k] = W[k][n]
  __shared__ _Float16 wa[2][128];          // wa[0]=W@a_src, wa[1]=W@a_dst

  int tid = threadIdx.x;

  // stage W transposed as fp16 (one-time; store conflicts acceptable)
  #pragma unroll
  for (int it = 0; it < 16; ++it) {
    int lin = it * 256 + tid;        // float4 index 0..4095
    int k  = lin >> 5;               // 0..127
    int n4 = (lin & 31) * 4;         // 0..124
    float4 v = *(const float4*)&W[(size_t)k * D + n4];
    Wt[n4 + 0][k] = (_Float16)v.x;
    Wt[n4 + 1][k] = (_Float16)v.y;
    Wt[n4 + 2][k] = (_Float16)v.z;
    Wt[n4 + 3][k] = (_Float16)v.w;
  }
  // wa = W @ a  (fp32 math, fp16 store)
  {
    int k = tid & 127;
    const float* vec = (tid < 128) ? avs : avd;
    float s = 0.f;
    #pragma unroll 8
    for (int n = 0; n < 128; n += 4) {
      float4 wv = *(const float4*)&W[(size_t)k * D + n];
      float4 av = *(const float4*)&vec[n];
      s += wv.x * av.x + wv.y * av.y + wv.z * av.z + wv.w * av.w;
    }
    wa[tid >> 7][k] = (_Float16)s;
  }
  __syncthreads();

  int wid = tid >> 6, lane = tid & 63;
  int quad = lane >> 4, nn = lane & 15;
  int row = blockIdx.x * 64 + wid * 16 + nn;
  int rowc = min(row, N - 1);

  v4f acc[9];
  #pragma unroll
  for (int t = 0; t < 9; ++t) acc[t] = (v4f){0.f, 0.f, 0.f, 0.f};

  #pragma unroll
  for (int ks = 0; ks < 4; ++ks) {
    int k0 = ks * 32 + quad * 8;
    v8h b;
    if (Xh) {
      b = *(const v8h*)&Xh[(size_t)rowc * D + k0];
    } else {
      float4 x0 = *(const float4*)&Xf[(size_t)rowc * D + k0];
      float4 x1 = *(const float4*)&Xf[(size_t)rowc * D + k0 + 4];
      b[0] = (_Float16)x0.x; b[1] = (_Float16)x0.y;
      b[2] = (_Float16)x0.z; b[3] = (_Float16)x0.w;
      b[4] = (_Float16)x1.x; b[5] = (_Float16)x1.y;
      b[6] = (_Float16)x1.z; b[7] = (_Float16)x1.w;
    }
    #pragma unroll
    for (int t = 0; t < 8; ++t) {
      v8h a = *(const v8h*)&Wt[t * 16 + nn][k0];
      acc[t] = __builtin_amdgcn_mfma_f32_16x16x32_f16(a, b, acc[t], 0, 0, 0);
    }
    v8h awv = *(const v8h*)&wa[nn & 1][k0];
    acc[8] = __builtin_amdgcn_mfma_f32_16x16x32_f16(awv, b, acc[8], 0, 0, 0);
  }

  if (row < N) {
    #pragma unroll
    for (int t = 0; t < 8; ++t) {
      __half2 h0 = __floats2half2_rn(acc[t].x, acc[t].y);
      __half2 h1 = __floats2half2_rn(acc[t].z, acc[t].w);
      *(__half2*)&H[(size_t)row * D + t * 16 + quad * 4]     = h0;
      *(__half2*)&H[(size_t)row * D + t * 16 + quad * 4 + 2] = h1;
    }
    if (quad == 0) { Ss[row] = acc[8].x; Sd[row] = acc[8].y; }
  }
}

// ---------------- per-dst softmax + aggregate ----------------
// one wave per dst node; lanes cover 2 channels each (half2 = 4B/edge).

__global__ __launch_bounds__(256) void agg_kernel(
    const __half* __restrict__ H, const float* __restrict__ Ssrc, const float* __restrict__ Sdst,
    const int* __restrict__ off, const int* __restrict__ csr, const float* __restrict__ bias,
    float* __restrict__ outF, __half* __restrict__ outH, int N, int do_relu)
{
  int wid = threadIdx.x >> 6, lane = threadIdx.x & 63;
  int n = blockIdx.x * 4 + wid;
  if (n >= N) return;
  int st = off[n], en = off[n + 1];
  float sd = Sdst[n];

  // pass 1: segment max of leaky-relu'd logits
  float m = -1e30f;
  for (int j = st + lane; j < en; j += 64) {
    int s = csr[j];
    float e = Ssrc[s] + sd;
    e = e > 0.f ? e : NEG_SLOPE * e;
    m = fmaxf(m, e);
  }
  #pragma unroll
  for (int o = 32; o; o >>= 1) m = fmaxf(m, __shfl_xor(m, o));

  // pass 2: unnormalized exp weights + gather-accumulate
  float z = 0.f, ax = 0.f, ay = 0.f;
  int c = lane * 2;
  for (int base = st; base < en; base += 64) {
    int j = base + lane;
    int cnt = min(64, en - base);        // >=1 (self-loops)
    float p = 0.f; int s = 0;
    if (j < en) {
      s = csr[j];
      float e = Ssrc[s] + sd;
      e = e > 0.f ? e : NEG_SLOPE * e;
      p = __expf(e - m);
    }
    z += p;
    for (int i = 0; i < cnt; i += 8) {
      float pu[8]; __half2 hv[8];
      #pragma unroll
      for (int u = 0; u < 8; ++u) {
        int idx = i + u;
        int iu = idx < cnt ? idx : cnt - 1;     // uniform clamp, no divergence
        float pb = __shfl(p, iu);               // v_readlane (uniform idx)
        int   sb = __shfl(s, iu);
        pu[u] = idx < cnt ? pb : 0.f;
        hv[u] = *(const __half2*)&H[(size_t)sb * D + c];
      }
      #pragma unroll
      for (int u = 0; u < 8; ++u) {
        float2 f = __half22float2(hv[u]);
        ax += pu[u] * f.x; ay += pu[u] * f.y;
      }
    }
  }
  #pragma unroll
  for (int o = 32; o; o >>= 1) z += __shfl_xor(z, o);
  float inv = 1.f / (z + 1e-16f);
  float2 bv = *(const float2*)&bias[c];
  ax = ax * inv + bv.x;
  ay = ay * inv + bv.y;
  if (do_relu) { ax = fmaxf(ax, 0.f); ay = fmaxf(ay, 0.f); }
  if (outH) {
    *(__half2*)&outH[(size_t)n * D + c] = __floats2half2_rn(ax, ay);
  } else {
    *(float2*)&outF[(size_t)n * D + c] = make_float2(ax, ay);
  }
}

// ---------------- launcher ----------------

extern "C" void kernel_launch(void* const* d_in, const int* in_sizes, int n_in,
                              void* d_out, int out_size, void* d_ws, size_t ws_size,
                              hipStream_t stream) {
  const float* x   = (const float*)d_in[0];
  const int*   ei  = (const int*)d_in[1];
  const float* W1  = (const float*)d_in[2];
  const float* as1 = (const float*)d_in[3];
  const float* ad1 = (const float*)d_in[4];
  const float* b1  = (const float*)d_in[5];
  const float* W2  = (const float*)d_in[6];
  const float* as2 = (const float*)d_in[7];
  const float* ad2 = (const float*)d_in[8];
  const float* b2  = (const float*)d_in[9];

  int N  = in_sizes[0] / D;
  int E  = in_sizes[1] / 2;
  int EP = E + N;
  const int* src = ei;
  const int* dst = ei + E;

  char* w = (char*)d_ws;
  auto alloc = [&](size_t bytes) -> char* {
    char* p = w; w += (bytes + 511) & ~(size_t)511; return p;
  };
  int NB = (N + 255) / 256;
  int*    deg   = (int*)alloc((size_t)N * 4);
  int*    off   = (int*)alloc(((size_t)N + 1) * 4);
  int*    csr   = (int*)alloc((size_t)EP * 4);
  int*    rank  = (int*)alloc((size_t)EP * 4);
  int*    psum  = (int*)alloc((size_t)NB * 4);
  int*    bbase = (int*)alloc((size_t)NB * 4);
  float*  ssrc  = (float*)alloc((size_t)N * 4);
  float*  sdst  = (float*)alloc((size_t)N * 4);
  __half* h     = (__half*)alloc((size_t)N * D * 2);
  __half* t1h   = (__half*)alloc((size_t)N * D * 2);

  hipMemsetAsync(deg, 0, (size_t)N * 4, stream);

  int nbGemm = (N + 63) / 64;         // 782
  int nbHist = 1024;

  // layer-1 GEMM (MFMA) overlapped with histogram+rank
  gemm_hist_fused<<<nbGemm + nbHist, 256, 0, stream>>>(
      x, nullptr, W1, as1, ad1, h, ssrc, sdst, N, dst, E, deg, rank, nbGemm, nbHist);

  // offsets + atomic-free scatter
  partial_kernel<<<NB, 256, 0, stream>>>(deg, psum, N);
  scan_partials<<<1, 1024, 0, stream>>>(psum, bbase, off, NB, N);
  offs_kernel<<<NB, 256, 0, stream>>>(deg, bbase, off, N);
  scatter_kernel<<<(EP + 255) / 256, 256, 0, stream>>>(src, dst, rank, E, N, off, csr);

  // layer 1 aggregate -> fp16 t1
  agg_kernel<<<(N + 3) / 4, 256, 0, stream>>>(h, ssrc, sdst, off, csr, b1,
                                              nullptr, t1h, N, 1);
  // layer 2: gemm reads fp16 t1 directly
  gemm_hist_fused<<<nbGemm, 256, 0, stream>>>(
      nullptr, t1h, W2, as2, ad2, h, ssrc, sdst, N, nullptr, 0, nullptr, nullptr, nbGemm, 0);
  agg_kernel<<<(N + 3) / 4, 256, 0, stream>>>(h, ssrc, sdst, off, csr, b2,
                                              (float*)d_out, nullptr, N, 0);
}